// Round 5
// baseline (237.744 us; speedup 1.0000x reference)
//
#include <hip/hip_runtime.h>
#include <stdint.h>

// Shapes: x[8,1024,1024] fp32; w[1024,1024] fp32 [in,out]; out[8,1024,1024] fp32
// B=8 P=1024 D=1024 H=16 Dh=64

typedef __attribute__((ext_vector_type(8))) short short8;   // 8 x bf16
typedef __attribute__((ext_vector_type(4))) short s16x4;    // 4 x bf16
typedef __attribute__((ext_vector_type(4))) float f32x4;

__device__ __forceinline__ short f2bf(float f) {
  unsigned u = __builtin_bit_cast(unsigned, f);
  u += 0x7fffu + ((u >> 16) & 1u);   // RNE
  return (short)(u >> 16);
}

// packed 2xfp32 -> 2xbf16 in one 32-bit word (a low 16, b high 16)
__device__ __forceinline__ unsigned pk2bf(float a, float b) {
  unsigned ua = __builtin_bit_cast(unsigned, a);
  unsigned ub = __builtin_bit_cast(unsigned, b);
  ua += 0x7fffu + ((ua >> 16) & 1u);
  ub += 0x7fffu + ((ub >> 16) & 1u);
  return (ua >> 16) | (ub & 0xffff0000u);
}

// hardware packed bf16 convert (1 VALU op instead of ~6)
__device__ __forceinline__ unsigned cvtpk(float a, float b) {
  unsigned r;
  asm("v_cvt_pk_bf16_f32 %0, %1, %2" : "=v"(r) : "v"(a), "v"(b));
  return r;
}

// hardware exp2 (scores are pre-scaled by log2(e)/8 in the QKV GEMM epilogue)
__device__ __forceinline__ float fexp2(float x) {
  float r;
  asm("v_exp_f32 %0, %1" : "=v"(r) : "v"(x));
  return r;
}

typedef __attribute__((address_space(3))) void lds_void;
typedef __attribute__((address_space(1))) void gbl_void;
#define GLD16(gp, lp) \
  __builtin_amdgcn_global_load_lds((gbl_void*)(gp), (lds_void*)(lp), 16, 0, 0)

#define MFMA(a, b, c) __builtin_amdgcn_mfma_f32_16x16x32_bf16((a), (b), (c), 0, 0, 0)

// ---------------- prep: x convert (z=4) + 4 weight transposes (z=0..3), one launch ----------------
// R4 (proven): transpose retiled 64x32, packed int stores (2 bf16/lane). Convert path 512 blocks x 8.
__global__ __launch_bounds__(256) void k_prep(const float* __restrict__ x,
                                              short* __restrict__ xb,
                                              const float* __restrict__ s0,
                                              const float* __restrict__ s1,
                                              const float* __restrict__ s2,
                                              const float* __restrict__ s3,
                                              short* __restrict__ d0,
                                              short* __restrict__ d1,
                                              short* __restrict__ d2,
                                              short* __restrict__ d3) {
  if (blockIdx.z == 4) {
    int t = threadIdx.y * 32 + threadIdx.x;
    int bid = blockIdx.y * 32 + blockIdx.x;   // 0..511
#pragma unroll
    for (int j = 0; j < 8; ++j) {
      int i = (bid * 2048 + j * 256 + t) * 8;
      const float4* s = (const float4*)(x + i);
      float4 f0 = s[0], f1 = s[1];
      short8 o;
      o[0] = f2bf(f0.x); o[1] = f2bf(f0.y); o[2] = f2bf(f0.z); o[3] = f2bf(f0.w);
      o[4] = f2bf(f1.x); o[5] = f2bf(f1.y); o[6] = f2bf(f1.z); o[7] = f2bf(f1.w);
      *(short8*)(xb + i) = o;
    }
    return;
  }
  __shared__ float tile[64][33];
  const float* srcs[4] = {s0, s1, s2, s3};
  short* dsts[4] = {d0, d1, d2, d3};
  const float* src = srcs[blockIdx.z];
  short* dst = dsts[blockIdx.z];
  int tx = threadIdx.x, ty = threadIdx.y;
  int x0 = blockIdx.x * 32, y0 = blockIdx.y * 64;
#pragma unroll
  for (int i = 0; i < 64; i += 8)
    tile[ty + i][tx] = src[(y0 + ty + i) * 1024 + x0 + tx];
  __syncthreads();
#pragma unroll
  for (int i = 0; i < 32; i += 8) {
    int r = ty + i;
    *(int*)&dst[(x0 + r) * 1024 + y0 + 2 * tx] =
        (int)pk2bf(tile[2 * tx][r], tile[2 * tx + 1][r]);
  }
}

// ---------------- bf16 GEMM, BK=64, swizzled LDS, 3 blocks/CU, XCD-aware block map ----------------
// (PROVEN structure. R2's 256x256 restructure regressed: 384-block quantization + 1-phase.
//  Per m99-m141 evidence, source-level pipelining at 128^2 w/ 3 blocks/CU is neutral — keep.)
// MODE 0 (fused QKV, N=3072): q,k -> [B*H][P][64] bf16 (q pre-scaled log2e/8);
//                             v -> [B*H][64][P] bf16 (V^T).
// MODE 1 (final, N=1024): fp32 row-major + bias.
template <int MODE>
__global__ __launch_bounds__(256, 3) void k_gemm(const short* __restrict__ A,
                                                 const short* __restrict__ Bt,
                                                 const float* __restrict__ bias0,
                                                 const float* __restrict__ bias1,
                                                 const float* __restrict__ bias2,
                                                 short* __restrict__ o0,
                                                 short* __restrict__ o1,
                                                 short* __restrict__ o2,
                                                 float* __restrict__ of) {
  __shared__ __align__(16) short a_lds[128 * 64];
  __shared__ __align__(16) short b_lds[128 * 64];
  const int tid = threadIdx.x;
  const int l = blockIdx.x;
  const int m0 = ((((l & 7) << 3) | ((l >> 3) & 7))) << 7;
  const int n0 = (l >> 6) << 7;
  const int w = tid >> 6;
  const int lane = tid & 63;
  const int ll = lane & 15;
  const int qd = lane >> 4;
  const int wm = (w & 1) * 64;
  const int wn = (w >> 1) * 64;

  const int srow = tid >> 3;
  const int schunk = ((tid & 7) ^ (srow & 7)) * 8;
  const short* ag = A + (long)(m0 + srow) * 1024 + schunk;
  const short* bg = Bt + (long)(n0 + srow) * 1024 + schunk;

  f32x4 acc[4][4] = {};

  for (int kt = 0; kt < 1024; kt += 64) {
#pragma unroll
    for (int j = 0; j < 4; ++j) {
      GLD16(ag + j * 32768 + kt, &a_lds[j * 2048 + tid * 8]);
      GLD16(bg + j * 32768 + kt, &b_lds[j * 2048 + tid * 8]);
    }
    __syncthreads();
#pragma unroll
    for (int kh = 0; kh < 2; ++kh) {
      const int xoff = (((kh * 4 + qd) ^ (ll & 7)) * 8);
      short8 af[4], bfr[4];
#pragma unroll
      for (int mt = 0; mt < 4; ++mt)
        af[mt] = *(const short8*)&a_lds[(wm + mt * 16 + ll) * 64 + xoff];
#pragma unroll
      for (int nt = 0; nt < 4; ++nt)
        bfr[nt] = *(const short8*)&b_lds[(wn + nt * 16 + ll) * 64 + xoff];
#pragma unroll
      for (int mt = 0; mt < 4; ++mt)
#pragma unroll
        for (int nt = 0; nt < 4; ++nt)
          acc[mt][nt] = MFMA(af[mt], bfr[nt], acc[mt][nt]);
    }
    __syncthreads();
  }

  if (MODE == 0) {
#pragma unroll
    for (int nt = 0; nt < 4; ++nt) {
      int n = n0 + wn + nt * 16 + ll;
      int which = n >> 10;
      int nl = n & 1023;
      int h = nl >> 6, d = n & 63;
      if (which == 2) {                    // V^T: [bh][64][p]
        float bv = bias2[nl];
        const int b = m0 >> 10;
        const int p0 = (m0 & 1023) + wm;
#pragma unroll
        for (int mt = 0; mt < 4; ++mt) {
          int p = p0 + mt * 16 + qd * 4;
          int2 pk;
          pk.x = (int)pk2bf(acc[mt][nt][0] + bv, acc[mt][nt][1] + bv);
          pk.y = (int)pk2bf(acc[mt][nt][2] + bv, acc[mt][nt][3] + bv);
          *(int2*)&o2[(long)(b * 16 + h) * 65536 + d * 1024 + p] = pk;
        }
      } else {                             // Q,K: [bh][p][64]
        float bv = (which == 0) ? bias0[nl] : bias1[nl];
        // Q pre-scale: 1/sqrt(64) * log2(e), so attention can use raw v_exp_f32 (exp2)
        float sc = (which == 0) ? 0.18033688f : 1.0f;
        short* o = (which == 0) ? o0 : o1;
#pragma unroll
        for (int mt = 0; mt < 4; ++mt) {
#pragma unroll
          for (int r = 0; r < 4; ++r) {
            int m = m0 + wm + mt * 16 + qd * 4 + r;
            int b = m >> 10, p = m & 1023;
            o[(long)(b * 16 + h) * 65536 + p * 64 + d] = f2bf((acc[mt][nt][r] + bv) * sc);
          }
        }
      }
    }
  } else {
#pragma unroll
    for (int nt = 0; nt < 4; ++nt) {
      int n = n0 + wn + nt * 16 + ll;
      float bv = bias0[n];
#pragma unroll
      for (int mt = 0; mt < 4; ++mt) {
#pragma unroll
        for (int r = 0; r < 4; ++r) {
          int m = m0 + wm + mt * 16 + qd * 4 + r;
          of[(long)m * 1024 + n] = acc[mt][nt][r] + bv;
        }
      }
    }
  }
}

// ---------------- flash attention v8 ----------------
// v6 math VERBATIM (in-register P via key-permuted K, exp2, cvtpk, setprio — proven 3x).
// v8 changes ONLY the staging/sync skeleton: v6's per-iter __syncthreads drained
// vmcnt(0), killing its own prefetch every iteration (loads never crossed a barrier).
// Now: 3 LDS buffers [c%3], per iter {s_waitcnt vmcnt(4); s_barrier; STAGE(c+2); compute(c)}.
// vmcnt(4) waits only tile c's 4 wave-loads (FIFO, m135); tile c+1's 4 stay in flight
// ACROSS the barrier -> each tile gets a 2-iteration latency budget (T3/T4 mechanism).
// Hazards: WAR — STAGE(c+2) hits buf[(c-1)%3]; its readers (iter c-1) finished before
// the barrier the stage follows. RAW — own loads via vmcnt(4), other waves' via barrier.
// Tail: iter 15 uses vmcnt(0). LDS 48KB -> 3 blocks/CU (launch_bounds(256,3)).
__global__ __launch_bounds__(256, 3) void k_attn(const short* __restrict__ Q,
                                                 const short* __restrict__ K,
                                                 const short* __restrict__ VT,
                                                 short* __restrict__ O) {
  __shared__ __align__(16) short k_lds[3][4096];    // [64 key(permuted)][64 d] swizzled
  __shared__ __align__(16) short vt_lds[3][4096];   // [64 d][64 key] swizzled
  const int tid = threadIdx.x;
  const int w = tid >> 6, lane = tid & 63, ll = lane & 15, qd = lane >> 4;
  const int bid = blockIdx.x;
  const int xcd = bid & 7;
  const int inner = bid >> 3;
  const int bh = xcd * 16 + (inner & 15);
  const int qb = inner >> 4;
  const long hoff = (long)bh * 65536;
  const int qr0 = qb * 128 + w * 32;

  const short* qg = Q + hoff + (long)(qr0 + ll) * 64 + qd * 8;
  short8 qf[2][2];
  qf[0][0] = *(const short8*)qg;
  qf[0][1] = *(const short8*)(qg + 32);
  qf[1][0] = *(const short8*)(qg + 1024);
  qf[1][1] = *(const short8*)(qg + 1024 + 32);

  const int sr = tid >> 3;
  const int swz = (tid & 7) ^ (sr & 7);
  // key permutation: LDS row sr <- global key pr(sr); pr bits = [o5][o3 o2][o4][o1 o0]
  const int pr = (sr & 0x23) | ((sr & 0x0C) << 1) | ((sr & 0x10) >> 2);
  const short* kg = K + hoff + pr * 64 + swz * 8;          // pr(sr+32)=pr(sr)+32
  const short* vg = VT + hoff + (long)sr * 1024 + swz * 8;

  const int swzr = ll & 7;
  const int fro0 = ll * 64 + ((qd ^ swzr) * 8);
  const int fro1 = ll * 64 + (((4 + qd) ^ swzr) * 8);

  f32x4 oacc[2][4] = {};
  float l_part[2] = {0.f, 0.f};

#define ASTAGE(t, bidx)                                              \
  {                                                                  \
    GLD16(kg + (t) * 4096, &k_lds[bidx][tid * 8]);                   \
    GLD16(kg + (t) * 4096 + 2048, &k_lds[bidx][2048 + tid * 8]);     \
    GLD16(vg + (t) * 64, &vt_lds[bidx][tid * 8]);                    \
    GLD16(vg + (t) * 64 + 32768, &vt_lds[bidx][2048 + tid * 8]);     \
  }

#define ACOMPUTE(cur)                                                        \
  {                                                                          \
    f32x4 s[2][4];                                                           \
    __builtin_amdgcn_s_setprio(1);                                           \
    _Pragma("unroll")                                                        \
    for (int jt = 0; jt < 4; ++jt) {                                         \
      short8 kf0 = *(const short8*)&k_lds[cur][jt * 1024 + fro0];            \
      short8 kf1 = *(const short8*)&k_lds[cur][jt * 1024 + fro1];            \
      f32x4 t0 = {};                                                         \
      t0 = MFMA(kf0, qf[0][0], t0);                                          \
      t0 = MFMA(kf1, qf[0][1], t0);                                          \
      s[0][jt] = t0;                                                         \
      f32x4 t1 = {};                                                         \
      t1 = MFMA(kf0, qf[1][0], t1);                                          \
      t1 = MFMA(kf1, qf[1][1], t1);                                          \
      s[1][jt] = t1;                                                         \
    }                                                                        \
    __builtin_amdgcn_s_setprio(0);                                           \
    short8 pf[2][2];                                                         \
    _Pragma("unroll")                                                        \
    for (int g = 0; g < 2; ++g) {                                            \
      float rs = 0.f;                                                        \
      _Pragma("unroll")                                                      \
      for (int jt = 0; jt < 4; ++jt)                                         \
        _Pragma("unroll")                                                    \
        for (int r = 0; r < 4; ++r) {                                        \
          float e = fexp2(s[g][jt][r]);                                      \
          s[g][jt][r] = e;                                                   \
          rs += e;                                                           \
        }                                                                    \
      l_part[g] += rs;                                                       \
      _Pragma("unroll")                                                      \
      for (int u = 0; u < 2; ++u) {                                          \
        union { short8 v; unsigned x[4]; } pk;                               \
        pk.x[0] = cvtpk(s[g][2 * u][0], s[g][2 * u][1]);                     \
        pk.x[1] = cvtpk(s[g][2 * u][2], s[g][2 * u][3]);                     \
        pk.x[2] = cvtpk(s[g][2 * u + 1][0], s[g][2 * u + 1][1]);             \
        pk.x[3] = cvtpk(s[g][2 * u + 1][2], s[g][2 * u + 1][3]);             \
        pf[g][u] = pk.v;                                                     \
      }                                                                      \
    }                                                                        \
    __builtin_amdgcn_s_setprio(1);                                           \
    _Pragma("unroll")                                                        \
    for (int dt = 0; dt < 4; ++dt) {                                         \
      short8 vf0 = *(const short8*)&vt_lds[cur][dt * 1024 + fro0];           \
      short8 vf1 = *(const short8*)&vt_lds[cur][dt * 1024 + fro1];           \
      oacc[0][dt] = MFMA(vf0, pf[0][0], oacc[0][dt]);                        \
      oacc[0][dt] = MFMA(vf1, pf[0][1], oacc[0][dt]);                        \
      oacc[1][dt] = MFMA(vf0, pf[1][0], oacc[1][dt]);                        \
      oacc[1][dt] = MFMA(vf1, pf[1][1], oacc[1][dt]);                        \
    }                                                                        \
    __builtin_amdgcn_s_setprio(0);                                           \
  }

  // prologue: tiles 0,1 in flight (8 wave-loads)
  ASTAGE(0, 0);
  ASTAGE(1, 1);

#pragma unroll 3
  for (int c = 0; c < 15; ++c) {
    asm volatile("s_waitcnt vmcnt(4)" ::: "memory");   // tile c landed (own loads, FIFO)
    __builtin_amdgcn_s_barrier();                      // all waves' tile c landed
    if (c < 14) ASTAGE(c + 2, (c + 2) % 3);            // buf[(c-1)%3]: readers done pre-barrier
    ACOMPUTE(c % 3);
  }
  asm volatile("s_waitcnt vmcnt(0)" ::: "memory");     // tail: tile 15
  __builtin_amdgcn_s_barrier();
  ACOMPUTE(0);                                         // 15 % 3 == 0

#undef ASTAGE
#undef ACOMPUTE

  const int b = bh >> 4, h = bh & 15;
#pragma unroll
  for (int g = 0; g < 2; ++g) {
    float l = l_part[g];
    l += __shfl_xor(l, 16, 64);
    l += __shfl_xor(l, 32, 64);
    const float inv = 1.0f / l;
    const long row = (long)(b * 1024 + qr0 + g * 16 + ll);
#pragma unroll
    for (int dt = 0; dt < 4; ++dt) {
      int2 ov;
      ov.x = (int)cvtpk(oacc[g][dt][0] * inv, oacc[g][dt][1] * inv);
      ov.y = (int)cvtpk(oacc[g][dt][2] * inv, oacc[g][dt][3] * inv);
      *(int2*)&O[row * 1024 + h * 64 + dt * 16 + qd * 4] = ov;
    }
  }
}

extern "C" void kernel_launch(void* const* d_in, const int* in_sizes, int n_in,
                              void* d_out, int out_size, void* d_ws, size_t ws_size,
                              hipStream_t stream) {
  const float* x   = (const float*)d_in[0];
  const float* w_q = (const float*)d_in[1];
  const float* b_q = (const float*)d_in[2];
  const float* w_k = (const float*)d_in[3];
  const float* b_k = (const float*)d_in[4];
  const float* w_v = (const float*)d_in[5];
  const float* b_v = (const float*)d_in[6];
  const float* w_o = (const float*)d_in[7];
  const float* b_o = (const float*)d_in[8];

  char* ws = (char*)d_ws;
  short* xb    = (short*)(ws);                   // 16 MB; reused as attn-out
  short* wqkvT = (short*)(ws + (16ull << 20));   // 6 MB [3072][1024]
  short* woT   = (short*)(ws + (22ull << 20));   // 2 MB
  short* qw    = (short*)(ws + (24ull << 20));   // 16 MB each
  short* kw    = (short*)(ws + (40ull << 20));
  short* vw    = (short*)(ws + (56ull << 20));   // V^T [bh][64][1024]

  k_prep<<<dim3(32, 16, 5), dim3(32, 8), 0, stream>>>(
      x, xb, w_q, w_k, w_v, w_o,
      wqkvT, wqkvT + (1 << 20), wqkvT + (2 << 20), woT);

  // fused QKV: N=3072, 1536 blocks, XCD-swizzled (proven)
  k_gemm<0><<<1536, 256, 0, stream>>>(xb, wqkvT, b_q, b_k, b_v,
                                      qw, kw, vw, nullptr);

  // 1-D grid, XCD swizzle: xcd owns bh range [xcd*16, xcd*16+16)
  k_attn<<<dim3(1024), 256, 0, stream>>>(qw, kw, vw, xb);

  // final projection: N=1024, 512 blocks, XCD-swizzled
  k_gemm<1><<<512, 256, 0, stream>>>(xb, woT, b_o, nullptr, nullptr,
                                     nullptr, nullptr, nullptr, (float*)d_out);
}

// Round 6
// 232.303 us; speedup vs baseline: 1.0234x; 1.0234x over previous
//
#include <hip/hip_runtime.h>
#include <stdint.h>

// Shapes: x[8,1024,1024] fp32; w[1024,1024] fp32 [in,out]; out[8,1024,1024] fp32
// B=8 P=1024 D=1024 H=16 Dh=64

typedef __attribute__((ext_vector_type(8))) short short8;   // 8 x bf16
typedef __attribute__((ext_vector_type(4))) short s16x4;    // 4 x bf16
typedef __attribute__((ext_vector_type(4))) float f32x4;

__device__ __forceinline__ short f2bf(float f) {
  unsigned u = __builtin_bit_cast(unsigned, f);
  u += 0x7fffu + ((u >> 16) & 1u);   // RNE
  return (short)(u >> 16);
}

// packed 2xfp32 -> 2xbf16 in one 32-bit word (a low 16, b high 16)
__device__ __forceinline__ unsigned pk2bf(float a, float b) {
  unsigned ua = __builtin_bit_cast(unsigned, a);
  unsigned ub = __builtin_bit_cast(unsigned, b);
  ua += 0x7fffu + ((ua >> 16) & 1u);
  ub += 0x7fffu + ((ub >> 16) & 1u);
  return (ua >> 16) | (ub & 0xffff0000u);
}

// hardware packed bf16 convert (1 VALU op instead of ~6)
__device__ __forceinline__ unsigned cvtpk(float a, float b) {
  unsigned r;
  asm("v_cvt_pk_bf16_f32 %0, %1, %2" : "=v"(r) : "v"(a), "v"(b));
  return r;
}

// hardware exp2 (scores are pre-scaled by log2(e)/8 in the QKV GEMM epilogue)
__device__ __forceinline__ float fexp2(float x) {
  float r;
  asm("v_exp_f32 %0, %1" : "=v"(r) : "v"(x));
  return r;
}

typedef __attribute__((address_space(3))) void lds_void;
typedef __attribute__((address_space(1))) void gbl_void;
#define GLD16(gp, lp) \
  __builtin_amdgcn_global_load_lds((gbl_void*)(gp), (lds_void*)(lp), 16, 0, 0)

#define MFMA(a, b, c) __builtin_amdgcn_mfma_f32_16x16x32_bf16((a), (b), (c), 0, 0, 0)

// ---------------- prep: x convert (z=4) + 4 weight transposes (z=0..3), one launch ----------------
// R4 (proven): transpose retiled 64x32, packed int stores (2 bf16/lane). Convert path 512 blocks x 8.
__global__ __launch_bounds__(256) void k_prep(const float* __restrict__ x,
                                              short* __restrict__ xb,
                                              const float* __restrict__ s0,
                                              const float* __restrict__ s1,
                                              const float* __restrict__ s2,
                                              const float* __restrict__ s3,
                                              short* __restrict__ d0,
                                              short* __restrict__ d1,
                                              short* __restrict__ d2,
                                              short* __restrict__ d3) {
  if (blockIdx.z == 4) {
    int t = threadIdx.y * 32 + threadIdx.x;
    int bid = blockIdx.y * 32 + blockIdx.x;   // 0..511
#pragma unroll
    for (int j = 0; j < 8; ++j) {
      int i = (bid * 2048 + j * 256 + t) * 8;
      const float4* s = (const float4*)(x + i);
      float4 f0 = s[0], f1 = s[1];
      short8 o;
      o[0] = f2bf(f0.x); o[1] = f2bf(f0.y); o[2] = f2bf(f0.z); o[3] = f2bf(f0.w);
      o[4] = f2bf(f1.x); o[5] = f2bf(f1.y); o[6] = f2bf(f1.z); o[7] = f2bf(f1.w);
      *(short8*)(xb + i) = o;
    }
    return;
  }
  __shared__ float tile[64][33];
  const float* srcs[4] = {s0, s1, s2, s3};
  short* dsts[4] = {d0, d1, d2, d3};
  const float* src = srcs[blockIdx.z];
  short* dst = dsts[blockIdx.z];
  int tx = threadIdx.x, ty = threadIdx.y;
  int x0 = blockIdx.x * 32, y0 = blockIdx.y * 64;
#pragma unroll
  for (int i = 0; i < 64; i += 8)
    tile[ty + i][tx] = src[(y0 + ty + i) * 1024 + x0 + tx];
  __syncthreads();
#pragma unroll
  for (int i = 0; i < 32; i += 8) {
    int r = ty + i;
    *(int*)&dst[(x0 + r) * 1024 + y0 + 2 * tx] =
        (int)pk2bf(tile[2 * tx][r], tile[2 * tx + 1][r]);
  }
}

// ---------------- bf16 GEMM, BK=64, swizzled LDS, 3 blocks/CU, XCD-aware block map ----------------
// (PROVEN structure; 128^2 additive menu exhausted per m99-m141/m190/m137 nulls.
//  R2's 256^2 1-phase restructure regressed: grid quantization + missing 8-phase. Keep.)
// MODE 0 (fused QKV, N=3072): q,k -> [B*H][P][64] bf16 (q pre-scaled log2e/8);
//                             v -> [B*H][64][P] bf16 (V^T).
// MODE 1 (final, N=1024): fp32 row-major + bias.
template <int MODE>
__global__ __launch_bounds__(256, 3) void k_gemm(const short* __restrict__ A,
                                                 const short* __restrict__ Bt,
                                                 const float* __restrict__ bias0,
                                                 const float* __restrict__ bias1,
                                                 const float* __restrict__ bias2,
                                                 short* __restrict__ o0,
                                                 short* __restrict__ o1,
                                                 short* __restrict__ o2,
                                                 float* __restrict__ of) {
  __shared__ __align__(16) short a_lds[128 * 64];
  __shared__ __align__(16) short b_lds[128 * 64];
  const int tid = threadIdx.x;
  const int l = blockIdx.x;
  const int m0 = ((((l & 7) << 3) | ((l >> 3) & 7))) << 7;
  const int n0 = (l >> 6) << 7;
  const int w = tid >> 6;
  const int lane = tid & 63;
  const int ll = lane & 15;
  const int qd = lane >> 4;
  const int wm = (w & 1) * 64;
  const int wn = (w >> 1) * 64;

  const int srow = tid >> 3;
  const int schunk = ((tid & 7) ^ (srow & 7)) * 8;
  const short* ag = A + (long)(m0 + srow) * 1024 + schunk;
  const short* bg = Bt + (long)(n0 + srow) * 1024 + schunk;

  f32x4 acc[4][4] = {};

  for (int kt = 0; kt < 1024; kt += 64) {
#pragma unroll
    for (int j = 0; j < 4; ++j) {
      GLD16(ag + j * 32768 + kt, &a_lds[j * 2048 + tid * 8]);
      GLD16(bg + j * 32768 + kt, &b_lds[j * 2048 + tid * 8]);
    }
    __syncthreads();
#pragma unroll
    for (int kh = 0; kh < 2; ++kh) {
      const int xoff = (((kh * 4 + qd) ^ (ll & 7)) * 8);
      short8 af[4], bfr[4];
#pragma unroll
      for (int mt = 0; mt < 4; ++mt)
        af[mt] = *(const short8*)&a_lds[(wm + mt * 16 + ll) * 64 + xoff];
#pragma unroll
      for (int nt = 0; nt < 4; ++nt)
        bfr[nt] = *(const short8*)&b_lds[(wn + nt * 16 + ll) * 64 + xoff];
#pragma unroll
      for (int mt = 0; mt < 4; ++mt)
#pragma unroll
        for (int nt = 0; nt < 4; ++nt)
          acc[mt][nt] = MFMA(af[mt], bfr[nt], acc[mt][nt]);
    }
    __syncthreads();
  }

  if (MODE == 0) {
#pragma unroll
    for (int nt = 0; nt < 4; ++nt) {
      int n = n0 + wn + nt * 16 + ll;
      int which = n >> 10;
      int nl = n & 1023;
      int h = nl >> 6, d = n & 63;
      if (which == 2) {                    // V^T: [bh][64][p]
        float bv = bias2[nl];
        const int b = m0 >> 10;
        const int p0 = (m0 & 1023) + wm;
#pragma unroll
        for (int mt = 0; mt < 4; ++mt) {
          int p = p0 + mt * 16 + qd * 4;
          int2 pk;
          pk.x = (int)pk2bf(acc[mt][nt][0] + bv, acc[mt][nt][1] + bv);
          pk.y = (int)pk2bf(acc[mt][nt][2] + bv, acc[mt][nt][3] + bv);
          *(int2*)&o2[(long)(b * 16 + h) * 65536 + d * 1024 + p] = pk;
        }
      } else {                             // Q,K: [bh][p][64]
        float bv = (which == 0) ? bias0[nl] : bias1[nl];
        // Q pre-scale: 1/sqrt(64) * log2(e), so attention can use raw v_exp_f32 (exp2)
        float sc = (which == 0) ? 0.18033688f : 1.0f;
        short* o = (which == 0) ? o0 : o1;
#pragma unroll
        for (int mt = 0; mt < 4; ++mt) {
#pragma unroll
          for (int r = 0; r < 4; ++r) {
            int m = m0 + wm + mt * 16 + qd * 4 + r;
            int b = m >> 10, p = m & 1023;
            o[(long)(b * 16 + h) * 65536 + p * 64 + d] = f2bf((acc[mt][nt][r] + bv) * sc);
          }
        }
      }
    }
  } else {
#pragma unroll
    for (int nt = 0; nt < 4; ++nt) {
      int n = n0 + wn + nt * 16 + ll;
      float bv = bias0[n];
#pragma unroll
      for (int mt = 0; mt < 4; ++mt) {
#pragma unroll
        for (int r = 0; r < 4; ++r) {
          int m = m0 + wm + mt * 16 + qd * 4 + r;
          of[(long)m * 1024 + n] = acc[mt][nt][r] + bv;
        }
      }
    }
  }
}

// ---------------- flash attention v6 (R1/R4-proven; best-known) ----------------
// In-register P via key-permuted K load, K/V double-buffer, exp2, cvtpk, setprio.
// LDS 32KB -> 4 blocks/CU. The per-iter __syncthreads drain is CHEAP here: the c+1
// prefetch is issued BEFORE compute(c), so loads get a full compute phase to fly
// (R5's 3-buffer counted-vmcnt variant regressed −17us: occupancy 4->3 + I-cache bloat).
// R3's PV-split variant NaN'd. Do not restructure this kernel's skeleton or the
// softmax/PV region without a within-run A/B and a race screen.
__global__ __launch_bounds__(256, 4) void k_attn(const short* __restrict__ Q,
                                                 const short* __restrict__ K,
                                                 const short* __restrict__ VT,
                                                 short* __restrict__ O) {
  __shared__ __align__(16) short k_lds[2][4096];    // [64 key(permuted)][64 d] swizzled
  __shared__ __align__(16) short vt_lds[2][4096];   // [64 d][64 key] swizzled
  const int tid = threadIdx.x;
  const int w = tid >> 6, lane = tid & 63, ll = lane & 15, qd = lane >> 4;
  const int bid = blockIdx.x;
  const int xcd = bid & 7;
  const int inner = bid >> 3;
  const int bh = xcd * 16 + (inner & 15);
  const int qb = inner >> 4;
  const long hoff = (long)bh * 65536;
  const int qr0 = qb * 128 + w * 32;

  const short* qg = Q + hoff + (long)(qr0 + ll) * 64 + qd * 8;
  short8 qf[2][2];
  qf[0][0] = *(const short8*)qg;
  qf[0][1] = *(const short8*)(qg + 32);
  qf[1][0] = *(const short8*)(qg + 1024);
  qf[1][1] = *(const short8*)(qg + 1024 + 32);

  const int sr = tid >> 3;
  const int swz = (tid & 7) ^ (sr & 7);
  // key permutation: LDS row sr <- global key pr(sr); pr bits = [o5][o3 o2][o4][o1 o0]
  const int pr = (sr & 0x23) | ((sr & 0x0C) << 1) | ((sr & 0x10) >> 2);
  const short* kg = K + hoff + pr * 64 + swz * 8;          // pr(sr+32)=pr(sr)+32
  const short* vg = VT + hoff + (long)sr * 1024 + swz * 8;

  const int swzr = ll & 7;
  const int fro0 = ll * 64 + ((qd ^ swzr) * 8);
  const int fro1 = ll * 64 + (((4 + qd) ^ swzr) * 8);

  f32x4 oacc[2][4] = {};
  float l_part[2] = {0.f, 0.f};

  // prologue: stage tile 0
  GLD16(kg, &k_lds[0][tid * 8]);
  GLD16(kg + 2048, &k_lds[0][2048 + tid * 8]);
  GLD16(vg, &vt_lds[0][tid * 8]);
  GLD16(vg + 32768, &vt_lds[0][2048 + tid * 8]);
  __syncthreads();

#pragma unroll 2
  for (int c = 0; c < 16; ++c) {
    const int cur = c & 1, nxt = cur ^ 1;
    if (c < 15) {   // buf[nxt] was last read in iter c-1; the iter-(c-1) barrier protects it
      GLD16(kg + (c + 1) * 4096, &k_lds[nxt][tid * 8]);
      GLD16(kg + (c + 1) * 4096 + 2048, &k_lds[nxt][2048 + tid * 8]);
      GLD16(vg + (c + 1) * 64, &vt_lds[nxt][tid * 8]);
      GLD16(vg + (c + 1) * 64 + 32768, &vt_lds[nxt][2048 + tid * 8]);
    }

    f32x4 s[2][4];
    __builtin_amdgcn_s_setprio(1);
#pragma unroll
    for (int jt = 0; jt < 4; ++jt) {
      short8 kf0 = *(const short8*)&k_lds[cur][jt * 1024 + fro0];
      short8 kf1 = *(const short8*)&k_lds[cur][jt * 1024 + fro1];
      f32x4 t0 = {};
      t0 = MFMA(kf0, qf[0][0], t0);
      t0 = MFMA(kf1, qf[0][1], t0);
      s[0][jt] = t0;
      f32x4 t1 = {};
      t1 = MFMA(kf0, qf[1][0], t1);
      t1 = MFMA(kf1, qf[1][1], t1);
      s[1][jt] = t1;
    }
    __builtin_amdgcn_s_setprio(0);

    short8 pf[2][2];
#pragma unroll
    for (int g = 0; g < 2; ++g) {
      float rs = 0.f;
#pragma unroll
      for (int jt = 0; jt < 4; ++jt)
#pragma unroll
        for (int r = 0; r < 4; ++r) {
          float e = fexp2(s[g][jt][r]);
          s[g][jt][r] = e;
          rs += e;
        }
      l_part[g] += rs;
#pragma unroll
      for (int u = 0; u < 2; ++u) {
        union { short8 v; unsigned x[4]; } pk;
        pk.x[0] = cvtpk(s[g][2 * u][0], s[g][2 * u][1]);
        pk.x[1] = cvtpk(s[g][2 * u][2], s[g][2 * u][3]);
        pk.x[2] = cvtpk(s[g][2 * u + 1][0], s[g][2 * u + 1][1]);
        pk.x[3] = cvtpk(s[g][2 * u + 1][2], s[g][2 * u + 1][3]);
        pf[g][u] = pk.v;
      }
    }

    __builtin_amdgcn_s_setprio(1);
#pragma unroll
    for (int dt = 0; dt < 4; ++dt) {
      short8 vf0 = *(const short8*)&vt_lds[cur][dt * 1024 + fro0];
      short8 vf1 = *(const short8*)&vt_lds[cur][dt * 1024 + fro1];
      oacc[0][dt] = MFMA(vf0, pf[0][0], oacc[0][dt]);
      oacc[0][dt] = MFMA(vf1, pf[0][1], oacc[0][dt]);
      oacc[1][dt] = MFMA(vf0, pf[1][0], oacc[1][dt]);
      oacc[1][dt] = MFMA(vf1, pf[1][1], oacc[1][dt]);
    }
    __builtin_amdgcn_s_setprio(0);
    __syncthreads();   // drains vmcnt(0): tile c+1 landed; all waves done reading buf[cur]
  }

  const int b = bh >> 4, h = bh & 15;
#pragma unroll
  for (int g = 0; g < 2; ++g) {
    float l = l_part[g];
    l += __shfl_xor(l, 16, 64);
    l += __shfl_xor(l, 32, 64);
    const float inv = 1.0f / l;
    const long row = (long)(b * 1024 + qr0 + g * 16 + ll);
#pragma unroll
    for (int dt = 0; dt < 4; ++dt) {
      int2 ov;
      ov.x = (int)cvtpk(oacc[g][dt][0] * inv, oacc[g][dt][1] * inv);
      ov.y = (int)cvtpk(oacc[g][dt][2] * inv, oacc[g][dt][3] * inv);
      *(int2*)&O[row * 1024 + h * 64 + dt * 16 + qd * 4] = ov;
    }
  }
}

extern "C" void kernel_launch(void* const* d_in, const int* in_sizes, int n_in,
                              void* d_out, int out_size, void* d_ws, size_t ws_size,
                              hipStream_t stream) {
  const float* x   = (const float*)d_in[0];
  const float* w_q = (const float*)d_in[1];
  const float* b_q = (const float*)d_in[2];
  const float* w_k = (const float*)d_in[3];
  const float* b_k = (const float*)d_in[4];
  const float* w_v = (const float*)d_in[5];
  const float* b_v = (const float*)d_in[6];
  const float* w_o = (const float*)d_in[7];
  const float* b_o = (const float*)d_in[8];

  char* ws = (char*)d_ws;
  short* xb    = (short*)(ws);                   // 16 MB; reused as attn-out
  short* wqkvT = (short*)(ws + (16ull << 20));   // 6 MB [3072][1024]
  short* woT   = (short*)(ws + (22ull << 20));   // 2 MB
  short* qw    = (short*)(ws + (24ull << 20));   // 16 MB each
  short* kw    = (short*)(ws + (40ull << 20));
  short* vw    = (short*)(ws + (56ull << 20));   // V^T [bh][64][1024]

  k_prep<<<dim3(32, 16, 5), dim3(32, 8), 0, stream>>>(
      x, xb, w_q, w_k, w_v, w_o,
      wqkvT, wqkvT + (1 << 20), wqkvT + (2 << 20), woT);

  // fused QKV: N=3072, 1536 blocks, XCD-swizzled (proven)
  k_gemm<0><<<1536, 256, 0, stream>>>(xb, wqkvT, b_q, b_k, b_v,
                                      qw, kw, vw, nullptr);

  // 1-D grid, XCD swizzle: xcd owns bh range [xcd*16, xcd*16+16)
  k_attn<<<dim3(1024), 256, 0, stream>>>(qw, kw, vw, xb);

  // final projection: N=1024, 512 blocks, XCD-swizzled
  k_gemm<1><<<512, 256, 0, stream>>>(xb, woT, b_o, nullptr, nullptr,
                                     nullptr, nullptr, nullptr, (float*)d_out);
}

// Round 7
// 215.794 us; speedup vs baseline: 1.1017x; 1.0765x over previous
//
#include <hip/hip_runtime.h>
#include <stdint.h>

// Shapes: x[8,1024,1024] fp32; w[1024,1024] fp32 [in,out]; out[8,1024,1024] fp32
// B=8 P=1024 D=1024 H=16 Dh=64

typedef __attribute__((ext_vector_type(8))) short short8;   // 8 x bf16
typedef __attribute__((ext_vector_type(4))) short s16x4;    // 4 x bf16
typedef __attribute__((ext_vector_type(4))) float f32x4;

__device__ __forceinline__ short f2bf(float f) {
  unsigned u = __builtin_bit_cast(unsigned, f);
  u += 0x7fffu + ((u >> 16) & 1u);   // RNE
  return (short)(u >> 16);
}

// packed 2xfp32 -> 2xbf16 in one 32-bit word (a low 16, b high 16)
__device__ __forceinline__ unsigned pk2bf(float a, float b) {
  unsigned ua = __builtin_bit_cast(unsigned, a);
  unsigned ub = __builtin_bit_cast(unsigned, b);
  ua += 0x7fffu + ((ua >> 16) & 1u);
  ub += 0x7fffu + ((ub >> 16) & 1u);
  return (ua >> 16) | (ub & 0xffff0000u);
}

// hardware packed bf16 convert (1 VALU op instead of ~6)
__device__ __forceinline__ unsigned cvtpk(float a, float b) {
  unsigned r;
  asm("v_cvt_pk_bf16_f32 %0, %1, %2" : "=v"(r) : "v"(a), "v"(b));
  return r;
}

// hardware exp2 (scores are pre-scaled by log2(e)/8 in the QKV GEMM epilogue)
__device__ __forceinline__ float fexp2(float x) {
  float r;
  asm("v_exp_f32 %0, %1" : "=v"(r) : "v"(x));
  return r;
}

typedef __attribute__((address_space(3))) void lds_void;
typedef __attribute__((address_space(1))) void gbl_void;
#define GLD16(gp, lp) \
  __builtin_amdgcn_global_load_lds((gbl_void*)(gp), (lds_void*)(lp), 16, 0, 0)

#define MFMA(a, b, c) __builtin_amdgcn_mfma_f32_16x16x32_bf16((a), (b), (c), 0, 0, 0)

// ---------------- prep: x convert (z=4) + 4 weight transposes (z=0..3), one launch ----------------
// R4 (proven): transpose retiled 64x32, packed int stores (2 bf16/lane). Convert path 512 blocks x 8.
__global__ __launch_bounds__(256) void k_prep(const float* __restrict__ x,
                                              short* __restrict__ xb,
                                              const float* __restrict__ s0,
                                              const float* __restrict__ s1,
                                              const float* __restrict__ s2,
                                              const float* __restrict__ s3,
                                              short* __restrict__ d0,
                                              short* __restrict__ d1,
                                              short* __restrict__ d2,
                                              short* __restrict__ d3) {
  if (blockIdx.z == 4) {
    int t = threadIdx.y * 32 + threadIdx.x;
    int bid = blockIdx.y * 32 + blockIdx.x;   // 0..511
#pragma unroll
    for (int j = 0; j < 8; ++j) {
      int i = (bid * 2048 + j * 256 + t) * 8;
      const float4* s = (const float4*)(x + i);
      float4 f0 = s[0], f1 = s[1];
      short8 o;
      o[0] = f2bf(f0.x); o[1] = f2bf(f0.y); o[2] = f2bf(f0.z); o[3] = f2bf(f0.w);
      o[4] = f2bf(f1.x); o[5] = f2bf(f1.y); o[6] = f2bf(f1.z); o[7] = f2bf(f1.w);
      *(short8*)(xb + i) = o;
    }
    return;
  }
  __shared__ float tile[64][33];
  const float* srcs[4] = {s0, s1, s2, s3};
  short* dsts[4] = {d0, d1, d2, d3};
  const float* src = srcs[blockIdx.z];
  short* dst = dsts[blockIdx.z];
  int tx = threadIdx.x, ty = threadIdx.y;
  int x0 = blockIdx.x * 32, y0 = blockIdx.y * 64;
#pragma unroll
  for (int i = 0; i < 64; i += 8)
    tile[ty + i][tx] = src[(y0 + ty + i) * 1024 + x0 + tx];
  __syncthreads();
#pragma unroll
  for (int i = 0; i < 32; i += 8) {
    int r = ty + i;
    *(int*)&dst[(x0 + r) * 1024 + y0 + 2 * tx] =
        (int)pk2bf(tile[2 * tx][r], tile[2 * tx + 1][r]);
  }
}

// ---------------- bf16 GEMM, BK=64, swizzled LDS, 3 blocks/CU, XCD-aware block map ----------------
// (PROVEN structure; 128^2 additive menu exhausted per m99-m141/m190/m137 nulls.
//  R2's 256^2 1-phase restructure regressed: grid quantization + missing 8-phase. Keep.)
// MODE 0 (fused QKV, N=3072): q,k -> [B*H][P][64] bf16 (q pre-scaled log2e/8);
//                             v -> [B*H][64][P] bf16 (V^T).
// MODE 1 (final, N=1024): fp32 row-major + bias.
template <int MODE>
__global__ __launch_bounds__(256, 3) void k_gemm(const short* __restrict__ A,
                                                 const short* __restrict__ Bt,
                                                 const float* __restrict__ bias0,
                                                 const float* __restrict__ bias1,
                                                 const float* __restrict__ bias2,
                                                 short* __restrict__ o0,
                                                 short* __restrict__ o1,
                                                 short* __restrict__ o2,
                                                 float* __restrict__ of) {
  __shared__ __align__(16) short a_lds[128 * 64];
  __shared__ __align__(16) short b_lds[128 * 64];
  const int tid = threadIdx.x;
  const int l = blockIdx.x;
  const int m0 = ((((l & 7) << 3) | ((l >> 3) & 7))) << 7;
  const int n0 = (l >> 6) << 7;
  const int w = tid >> 6;
  const int lane = tid & 63;
  const int ll = lane & 15;
  const int qd = lane >> 4;
  const int wm = (w & 1) * 64;
  const int wn = (w >> 1) * 64;

  const int srow = tid >> 3;
  const int schunk = ((tid & 7) ^ (srow & 7)) * 8;
  const short* ag = A + (long)(m0 + srow) * 1024 + schunk;
  const short* bg = Bt + (long)(n0 + srow) * 1024 + schunk;

  f32x4 acc[4][4] = {};

  for (int kt = 0; kt < 1024; kt += 64) {
#pragma unroll
    for (int j = 0; j < 4; ++j) {
      GLD16(ag + j * 32768 + kt, &a_lds[j * 2048 + tid * 8]);
      GLD16(bg + j * 32768 + kt, &b_lds[j * 2048 + tid * 8]);
    }
    __syncthreads();
#pragma unroll
    for (int kh = 0; kh < 2; ++kh) {
      const int xoff = (((kh * 4 + qd) ^ (ll & 7)) * 8);
      short8 af[4], bfr[4];
#pragma unroll
      for (int mt = 0; mt < 4; ++mt)
        af[mt] = *(const short8*)&a_lds[(wm + mt * 16 + ll) * 64 + xoff];
#pragma unroll
      for (int nt = 0; nt < 4; ++nt)
        bfr[nt] = *(const short8*)&b_lds[(wn + nt * 16 + ll) * 64 + xoff];
#pragma unroll
      for (int mt = 0; mt < 4; ++mt)
#pragma unroll
        for (int nt = 0; nt < 4; ++nt)
          acc[mt][nt] = MFMA(af[mt], bfr[nt], acc[mt][nt]);
    }
    __syncthreads();
  }

  if (MODE == 0) {
#pragma unroll
    for (int nt = 0; nt < 4; ++nt) {
      int n = n0 + wn + nt * 16 + ll;
      int which = n >> 10;
      int nl = n & 1023;
      int h = nl >> 6, d = n & 63;
      if (which == 2) {                    // V^T: [bh][64][p]
        float bv = bias2[nl];
        const int b = m0 >> 10;
        const int p0 = (m0 & 1023) + wm;
#pragma unroll
        for (int mt = 0; mt < 4; ++mt) {
          int p = p0 + mt * 16 + qd * 4;
          int2 pk;
          pk.x = (int)pk2bf(acc[mt][nt][0] + bv, acc[mt][nt][1] + bv);
          pk.y = (int)pk2bf(acc[mt][nt][2] + bv, acc[mt][nt][3] + bv);
          *(int2*)&o2[(long)(b * 16 + h) * 65536 + d * 1024 + p] = pk;
        }
      } else {                             // Q,K: [bh][p][64]
        float bv = (which == 0) ? bias0[nl] : bias1[nl];
        // Q pre-scale: 1/sqrt(64) * log2(e), so attention can use raw v_exp_f32 (exp2)
        float sc = (which == 0) ? 0.18033688f : 1.0f;
        short* o = (which == 0) ? o0 : o1;
#pragma unroll
        for (int mt = 0; mt < 4; ++mt) {
#pragma unroll
          for (int r = 0; r < 4; ++r) {
            int m = m0 + wm + mt * 16 + qd * 4 + r;
            int b = m >> 10, p = m & 1023;
            o[(long)(b * 16 + h) * 65536 + p * 64 + d] = f2bf((acc[mt][nt][r] + bv) * sc);
          }
        }
      }
    }
  } else {
#pragma unroll
    for (int nt = 0; nt < 4; ++nt) {
      int n = n0 + wn + nt * 16 + ll;
      float bv = bias0[n];
#pragma unroll
      for (int mt = 0; mt < 4; ++mt) {
#pragma unroll
        for (int r = 0; r < 4; ++r) {
          int m = m0 + wm + mt * 16 + qd * 4 + r;
          of[(long)m * 1024 + n] = acc[mt][nt][r] + bv;
        }
      }
    }
  }
}

// ---------------- flash attention v9 ----------------
// v6 skeleton + math VERBATIM (in-register P via key-permuted K, dbuf, exp2, cvtpk,
// setprio — proven 4x; R3/R5 skeleton restructures both failed, keep frozen).
// v9's single change: ROWSUM VIA MFMA-ONES. The softmax denominator
// l[q] = sum_k P[k][q] is computed as lacc[g] = MFMA(ones16x32, pf[g][u], lacc[g])
// (ones matrix is layout-invariant; pf layout already proven by PV). C layout gives
// col=lane&15=ll=q, so lacc[g][0] IS this lane's denominator -> epilogue shuffles gone.
// Removes ~34 VALU adds/iter + 4 shuffle-adds from the busy pipe (R0: VALUBusy 45%);
// adds 4 MFMA/iter to the idle pipe (MfmaUtil 21%). Denominator now sums bf16-rounded
// P (matches the PV numerator; ~0.01% relative effect, threshold 2e-3).
__global__ __launch_bounds__(256, 4) void k_attn(const short* __restrict__ Q,
                                                 const short* __restrict__ K,
                                                 const short* __restrict__ VT,
                                                 short* __restrict__ O) {
  __shared__ __align__(16) short k_lds[2][4096];    // [64 key(permuted)][64 d] swizzled
  __shared__ __align__(16) short vt_lds[2][4096];   // [64 d][64 key] swizzled
  const int tid = threadIdx.x;
  const int w = tid >> 6, lane = tid & 63, ll = lane & 15, qd = lane >> 4;
  const int bid = blockIdx.x;
  const int xcd = bid & 7;
  const int inner = bid >> 3;
  const int bh = xcd * 16 + (inner & 15);
  const int qb = inner >> 4;
  const long hoff = (long)bh * 65536;
  const int qr0 = qb * 128 + w * 32;

  const short* qg = Q + hoff + (long)(qr0 + ll) * 64 + qd * 8;
  short8 qf[2][2];
  qf[0][0] = *(const short8*)qg;
  qf[0][1] = *(const short8*)(qg + 32);
  qf[1][0] = *(const short8*)(qg + 1024);
  qf[1][1] = *(const short8*)(qg + 1024 + 32);

  const int sr = tid >> 3;
  const int swz = (tid & 7) ^ (sr & 7);
  // key permutation: LDS row sr <- global key pr(sr); pr bits = [o5][o3 o2][o4][o1 o0]
  const int pr = (sr & 0x23) | ((sr & 0x0C) << 1) | ((sr & 0x10) >> 2);
  const short* kg = K + hoff + pr * 64 + swz * 8;          // pr(sr+32)=pr(sr)+32
  const short* vg = VT + hoff + (long)sr * 1024 + swz * 8;

  const int swzr = ll & 7;
  const int fro0 = ll * 64 + ((qd ^ swzr) * 8);
  const int fro1 = ll * 64 + (((4 + qd) ^ swzr) * 8);

  // bf16 1.0 ones-fragment for the rowsum MFMA (layout-invariant)
  short8 ones;
#pragma unroll
  for (int i = 0; i < 8; ++i) ones[i] = (short)0x3F80;

  f32x4 oacc[2][4] = {};
  f32x4 lacc[2] = {};

  // prologue: stage tile 0
  GLD16(kg, &k_lds[0][tid * 8]);
  GLD16(kg + 2048, &k_lds[0][2048 + tid * 8]);
  GLD16(vg, &vt_lds[0][tid * 8]);
  GLD16(vg + 32768, &vt_lds[0][2048 + tid * 8]);
  __syncthreads();

#pragma unroll 2
  for (int c = 0; c < 16; ++c) {
    const int cur = c & 1, nxt = cur ^ 1;
    if (c < 15) {   // buf[nxt] was last read in iter c-1; the iter-(c-1) barrier protects it
      GLD16(kg + (c + 1) * 4096, &k_lds[nxt][tid * 8]);
      GLD16(kg + (c + 1) * 4096 + 2048, &k_lds[nxt][2048 + tid * 8]);
      GLD16(vg + (c + 1) * 64, &vt_lds[nxt][tid * 8]);
      GLD16(vg + (c + 1) * 64 + 32768, &vt_lds[nxt][2048 + tid * 8]);
    }

    f32x4 s[2][4];
    __builtin_amdgcn_s_setprio(1);
#pragma unroll
    for (int jt = 0; jt < 4; ++jt) {
      short8 kf0 = *(const short8*)&k_lds[cur][jt * 1024 + fro0];
      short8 kf1 = *(const short8*)&k_lds[cur][jt * 1024 + fro1];
      f32x4 t0 = {};
      t0 = MFMA(kf0, qf[0][0], t0);
      t0 = MFMA(kf1, qf[0][1], t0);
      s[0][jt] = t0;
      f32x4 t1 = {};
      t1 = MFMA(kf0, qf[1][0], t1);
      t1 = MFMA(kf1, qf[1][1], t1);
      s[1][jt] = t1;
    }
    __builtin_amdgcn_s_setprio(0);

    short8 pf[2][2];
#pragma unroll
    for (int g = 0; g < 2; ++g) {
#pragma unroll
      for (int jt = 0; jt < 4; ++jt)
#pragma unroll
        for (int r = 0; r < 4; ++r)
          s[g][jt][r] = fexp2(s[g][jt][r]);
#pragma unroll
      for (int u = 0; u < 2; ++u) {
        union { short8 v; unsigned x[4]; } pk;
        pk.x[0] = cvtpk(s[g][2 * u][0], s[g][2 * u][1]);
        pk.x[1] = cvtpk(s[g][2 * u][2], s[g][2 * u][3]);
        pk.x[2] = cvtpk(s[g][2 * u + 1][0], s[g][2 * u + 1][1]);
        pk.x[3] = cvtpk(s[g][2 * u + 1][2], s[g][2 * u + 1][3]);
        pf[g][u] = pk.v;
      }
    }

    __builtin_amdgcn_s_setprio(1);
#pragma unroll
    for (int dt = 0; dt < 4; ++dt) {
      short8 vf0 = *(const short8*)&vt_lds[cur][dt * 1024 + fro0];
      short8 vf1 = *(const short8*)&vt_lds[cur][dt * 1024 + fro1];
      oacc[0][dt] = MFMA(vf0, pf[0][0], oacc[0][dt]);
      oacc[0][dt] = MFMA(vf1, pf[0][1], oacc[0][dt]);
      oacc[1][dt] = MFMA(vf0, pf[1][0], oacc[1][dt]);
      oacc[1][dt] = MFMA(vf1, pf[1][1], oacc[1][dt]);
    }
    // rowsum on the matrix pipe: lacc[g][r] = sum_k P[k][q=ll] (replicated over r)
    lacc[0] = MFMA(ones, pf[0][0], lacc[0]);
    lacc[0] = MFMA(ones, pf[0][1], lacc[0]);
    lacc[1] = MFMA(ones, pf[1][0], lacc[1]);
    lacc[1] = MFMA(ones, pf[1][1], lacc[1]);
    __builtin_amdgcn_s_setprio(0);
    __syncthreads();   // drains vmcnt(0): tile c+1 landed; all waves done reading buf[cur]
  }

  const int b = bh >> 4, h = bh & 15;
#pragma unroll
  for (int g = 0; g < 2; ++g) {
    const float inv = 1.0f / lacc[g][0];   // q=ll matches O row indexing; no shuffles
    const long row = (long)(b * 1024 + qr0 + g * 16 + ll);
#pragma unroll
    for (int dt = 0; dt < 4; ++dt) {
      int2 ov;
      ov.x = (int)cvtpk(oacc[g][dt][0] * inv, oacc[g][dt][1] * inv);
      ov.y = (int)cvtpk(oacc[g][dt][2] * inv, oacc[g][dt][3] * inv);
      *(int2*)&O[row * 1024 + h * 64 + dt * 16 + qd * 4] = ov;
    }
  }
}

extern "C" void kernel_launch(void* const* d_in, const int* in_sizes, int n_in,
                              void* d_out, int out_size, void* d_ws, size_t ws_size,
                              hipStream_t stream) {
  const float* x   = (const float*)d_in[0];
  const float* w_q = (const float*)d_in[1];
  const float* b_q = (const float*)d_in[2];
  const float* w_k = (const float*)d_in[3];
  const float* b_k = (const float*)d_in[4];
  const float* w_v = (const float*)d_in[5];
  const float* b_v = (const float*)d_in[6];
  const float* w_o = (const float*)d_in[7];
  const float* b_o = (const float*)d_in[8];

  char* ws = (char*)d_ws;
  short* xb    = (short*)(ws);                   // 16 MB; reused as attn-out
  short* wqkvT = (short*)(ws + (16ull << 20));   // 6 MB [3072][1024]
  short* woT   = (short*)(ws + (22ull << 20));   // 2 MB
  short* qw    = (short*)(ws + (24ull << 20));   // 16 MB each
  short* kw    = (short*)(ws + (40ull << 20));
  short* vw    = (short*)(ws + (56ull << 20));   // V^T [bh][64][1024]

  k_prep<<<dim3(32, 16, 5), dim3(32, 8), 0, stream>>>(
      x, xb, w_q, w_k, w_v, w_o,
      wqkvT, wqkvT + (1 << 20), wqkvT + (2 << 20), woT);

  // fused QKV: N=3072, 1536 blocks, XCD-swizzled (proven)
  k_gemm<0><<<1536, 256, 0, stream>>>(xb, wqkvT, b_q, b_k, b_v,
                                      qw, kw, vw, nullptr);

  // 1-D grid, XCD swizzle: xcd owns bh range [xcd*16, xcd*16+16)
  k_attn<<<dim3(1024), 256, 0, stream>>>(qw, kw, vw, xb);

  // final projection: N=1024, 512 blocks, XCD-swizzled
  k_gemm<1><<<512, 256, 0, stream>>>(xb, woT, b_o, nullptr, nullptr,
                                     nullptr, nullptr, nullptr, (float*)d_out);
}